// Round 2
// baseline (15432.997 us; speedup 1.0000x reference)
//
#include <hip/hip_runtime.h>
#include <cmath>

// Problem constants (fixed by the reference).
#define SEQ   4096
#define INP   1024
#define HID   1024
#define G4    4096   // 4*HID

// ---------------------------------------------------------------------------
// Kernel 1: xg[t][r] = dot(emb[inputs[t]], W_ih[r]) + b_ih[r] + b_hh[r]
// 64x64 output tile per block, 256 threads, 4x4 micro-tile, fp32 VALU.
// (unchanged this round)
// ---------------------------------------------------------------------------
__global__ __launch_bounds__(256) void xg_gemm_kernel(
    const int* __restrict__ inputs,
    const float* __restrict__ emb,
    const float* __restrict__ W_ih,
    const float* __restrict__ b_ih,
    const float* __restrict__ b_hh,
    float* __restrict__ xg)
{
    __shared__ __align__(16) float As[16][68];
    __shared__ __align__(16) float Bs[16][68];
    __shared__ int toks[64];

    const int tid = threadIdx.x;
    const int bt = blockIdx.y * 64;
    const int br = blockIdx.x * 64;

    if (tid < 64) toks[tid] = inputs[bt + tid];
    __syncthreads();

    const int tx = tid & 15;
    const int ty = tid >> 4;
    const int si = tid >> 2;
    const int sk = (tid & 3) * 4;

    float acc[4][4] = {};

    for (int kk = 0; kk < INP; kk += 16) {
        float4 av = *(const float4*)(emb  + (size_t)toks[si] * INP + kk + sk);
        float4 bv = *(const float4*)(W_ih + (size_t)(br + si) * INP + kk + sk);
        As[sk+0][si] = av.x; As[sk+1][si] = av.y; As[sk+2][si] = av.z; As[sk+3][si] = av.w;
        Bs[sk+0][si] = bv.x; Bs[sk+1][si] = bv.y; Bs[sk+2][si] = bv.z; Bs[sk+3][si] = bv.w;
        __syncthreads();
        #pragma unroll
        for (int k = 0; k < 16; ++k) {
            float4 a = *(const float4*)&As[k][ty * 4];
            float4 b = *(const float4*)&Bs[k][tx * 4];
            float ar[4] = {a.x, a.y, a.z, a.w};
            float brr[4] = {b.x, b.y, b.z, b.w};
            #pragma unroll
            for (int iy = 0; iy < 4; ++iy)
                #pragma unroll
                for (int ix = 0; ix < 4; ++ix)
                    acc[iy][ix] += ar[iy] * brr[ix];
        }
        __syncthreads();
    }

    const int r0 = br + tx * 4;
    float4 bias;
    bias.x = b_ih[r0+0] + b_hh[r0+0];
    bias.y = b_ih[r0+1] + b_hh[r0+1];
    bias.z = b_ih[r0+2] + b_hh[r0+2];
    bias.w = b_ih[r0+3] + b_hh[r0+3];
    #pragma unroll
    for (int iy = 0; iy < 4; ++iy) {
        float4 o;
        o.x = acc[iy][0] + bias.x;
        o.y = acc[iy][1] + bias.y;
        o.z = acc[iy][2] + bias.z;
        o.w = acc[iy][3] + bias.w;
        *(float4*)(xg + (size_t)(bt + ty * 4 + iy) * G4 + r0) = o;
    }
}

// ---------------------------------------------------------------------------
__device__ __forceinline__ float fast_sigmoid(float x) {
    x = fminf(fmaxf(x, -30.f), 30.f);
    return __builtin_amdgcn_rcpf(1.0f + __expf(-x));
}
__device__ __forceinline__ float fast_tanh(float x) {
    x = fminf(fmaxf(x, -15.f), 15.f);
    float e = __expf(2.0f * x);
    return (e - 1.0f) * __builtin_amdgcn_rcpf(e + 1.0f);
}

__device__ __forceinline__ unsigned long long mb_load(const unsigned long long* p) {
    return __hip_atomic_load(p, __ATOMIC_RELAXED, __HIP_MEMORY_SCOPE_AGENT);
}

// DPP cross-lane move (VALU pipe, not LDS). CTRL: 0xB1=xor1 (quad_perm
// [1,0,3,2]), 0x4E=xor2 ([2,3,0,1]), 0x124=row_ror:4, 0x128=row_ror:8.
template <int CTRL>
__device__ __forceinline__ float dpp_mov(float x) {
    return __int_as_float(__builtin_amdgcn_update_dpp(
        0, __float_as_int(x), CTRL, 0xF, 0xF, true));
}

// ---------------------------------------------------------------------------
// Kernel 2: persistent cooperative LSTM scan — 256 WGs x 256 threads.
//
// R2 redesign: R1 showed the bottleneck is per-SIMD issue serialization of
// the post-arrival burst (4 waves/SIMD x ~590cy VALU each ≈ 2350cy/step of
// the 5100cy step). Spread the SAME per-wave work (unchanged, bit-exact)
// over 4x the CUs: 1 WG/CU, 1 wave/SIMD.
//
// Wave wv (0..3) of WG w owns h element j = w*4+wv and its 4 gate rows
// {q*1024+j}. Lane (qq=lane>>4, kc=lane&15) computes partial dots for all
// 4 rows over its PRIVATE 16-element h slice h[kc*64+qq*16 .. +16) — same
// mapping, same FMA order, same DPP/shuffle butterfly as before, so h is
// bit-identical to the previous kernel.
//
// Mailbox unchanged: hbuf[parity(2)][1024] u64 (tag<<32 | f32bits). Each
// thread now polls 4 slots {tid+256k} (pipelined); each wave's lane 0
// publishes its single element directly after the gates (no hout staging,
// no B2 — hs/xgs are parity double-buffered instead; safety: a t+2 write
// to hs[par] is gated on tag t+2, which is causally after every wave
// finished its t-step reads of hs[par], via the producers' B1 at t+1).
// ---------------------------------------------------------------------------
__global__ __launch_bounds__(256, 1) void lstm_kernel(
    const float* __restrict__ xg,
    const float* __restrict__ W_hh,
    const float* __restrict__ h0,
    const float* __restrict__ c0,
    unsigned long long* __restrict__ hbuf,   // 2 * 1024 entries
    float* __restrict__ out)
{
    const int w    = blockIdx.x;   // 0..255
    const int tid  = threadIdx.x;  // 0..255
    const int lane = tid & 63;
    const int wv   = tid >> 6;     // wave 0..3 -> h element j = w*4+wv
    const int qq   = lane >> 4;    // 16-lane group 0..3 (h-slice quarter)
    const int kc   = lane & 15;    // 64-float h chunk index
    const int j    = w * 4 + wv;

    // Seed h0 with tag 0 (parity 0) first so consumers can start while we
    // load wreg. Lane 0 of each wave publishes its one element.
    if (lane == 0) {
        unsigned long long pk =
            (unsigned long long)__float_as_uint(h0[j]);
        __hip_atomic_store(hbuf + j, pk,
                           __ATOMIC_RELAXED, __HIP_MEMORY_SCOPE_AGENT);
    }

    // Persistent W fragment: wreg[q][e] = W_hh[q*1024+j][kc*64+qq*16+e].
    float wreg[4][16];
    {
        #pragma unroll
        for (int q = 0; q < 4; ++q) {
            const float* wp = W_hh + (size_t)(q * HID + j) * HID + kc * 64 + qq * 16;
            #pragma unroll
            for (int m = 0; m < 4; ++m) {
                float4 v = *(const float4*)(wp + 4 * m);
                wreg[q][4*m+0] = v.x; wreg[q][4*m+1] = v.y;
                wreg[q][4*m+2] = v.z; wreg[q][4*m+3] = v.w;
            }
        }
    }

    float c = c0[j];

    __shared__ __align__(16) float hs[2][16 * 68];  // parity-dbuf h, stride 68
    __shared__ float xgs[2][16];                    // parity-dbuf xg slice

    // This thread's 4 polled elements e_k = tid + 256k live at
    // chunk (tid>>6)+4k, offset tid&63 -> hs slot wofs + k*(4*68).
    const int wofs = (tid >> 6) * 68 + (tid & 63);
    const bool hasx = (tid < 16);
    // tid<16: q = tid>>2, elem = w*4 + (tid&3)
    const size_t xgofs = (size_t)(tid >> 2) * HID + w * 4 + (tid & 3);

    for (int t = 0; t < SEQ; ++t) {
        const int par = t & 1;
        const unsigned long long* slot = hbuf + (size_t)par * 1024 + tid;

        // xg load issued before the poll; latency hides under the wait.
        float xv = 0.f;
        if (hasx) xv = xg[(size_t)t * G4 + xgofs];

        // Pipelined poll of this thread's 4 slots.
        const unsigned int tg = (unsigned int)t;
        unsigned long long a0 = mb_load(slot);
        unsigned long long a1 = mb_load(slot + 256);
        unsigned long long a2 = mb_load(slot + 512);
        unsigned long long a3 = mb_load(slot + 768);
        unsigned mOK = 0u;
        while (mOK != 15u) {
            if (!(mOK & 1u)) { if ((unsigned)(a0 >> 32) == tg) mOK |= 1u; else a0 = mb_load(slot);       }
            if (!(mOK & 2u)) { if ((unsigned)(a1 >> 32) == tg) mOK |= 2u; else a1 = mb_load(slot + 256); }
            if (!(mOK & 4u)) { if ((unsigned)(a2 >> 32) == tg) mOK |= 4u; else a2 = mb_load(slot + 512); }
            if (!(mOK & 8u)) { if ((unsigned)(a3 >> 32) == tg) mOK |= 8u; else a3 = mb_load(slot + 768); }
        }

        float* hb = hs[par];
        hb[wofs           ] = __uint_as_float((unsigned)a0);
        hb[wofs +  4 * 68 ] = __uint_as_float((unsigned)a1);
        hb[wofs +  8 * 68 ] = __uint_as_float((unsigned)a2);
        hb[wofs + 12 * 68 ] = __uint_as_float((unsigned)a3);
        if (hasx) xgs[par][tid] = xv;
        __syncthreads();  // B1 (only barrier per step)

        // Partial dots for all 4 gate rows over the private 16-elem slice:
        // 4 ds_read_b128, all lanes distinct data. (identical to before)
        const float* hp = hb + kc * 68 + qq * 16;
        float p[4] = {0.f, 0.f, 0.f, 0.f};
        #pragma unroll
        for (int m = 0; m < 4; ++m) {
            float4 hv = *(const float4*)(hp + 4 * m);
            #pragma unroll
            for (int q = 0; q < 4; ++q) {
                p[q] += wreg[q][4*m+0] * hv.x;
                p[q] += wreg[q][4*m+1] * hv.y;
                p[q] += wreg[q][4*m+2] * hv.z;
                p[q] += wreg[q][4*m+3] * hv.w;
            }
        }

        // 64-lane butterfly reduction of the 4 accumulators (identical).
        #pragma unroll
        for (int q = 0; q < 4; ++q) {
            p[q] += dpp_mov<0xB1>(p[q]);
            p[q] += dpp_mov<0x4E>(p[q]);
            p[q] += dpp_mov<0x124>(p[q]);
            p[q] += dpp_mov<0x128>(p[q]);
            p[q] += __shfl_xor(p[q], 16);
            p[q] += __shfl_xor(p[q], 32);
        }

        float gi = p[0] + xgs[par][ 0 + wv];
        float gf = p[1] + xgs[par][ 4 + wv];
        float gg = p[2] + xgs[par][ 8 + wv];
        float go = p[3] + xgs[par][12 + wv];

        float ig = fast_sigmoid(gi);
        float fg = fast_sigmoid(gf);
        float gc = fast_tanh(gg);
        float og = fast_sigmoid(go);
        c = fg * c + ig * gc;
        float h = og * fast_tanh(c);

        // Each wave's lane 0 publishes its element directly. No B2 needed:
        // next step writes go to the other parity buffer.
        if (lane == 0) {
            unsigned long long pk =
                ((unsigned long long)(unsigned int)(t + 1) << 32) |
                (unsigned long long)__float_as_uint(h);
            __hip_atomic_store(
                hbuf + (size_t)((t + 1) & 1) * 1024 + j, pk,
                __ATOMIC_RELAXED, __HIP_MEMORY_SCOPE_AGENT);
        }
    }

    // ------------------- final log_softmax (WG 0 only) -------------------
    if (w != 0) return;

    // Poll the 4 final values (tag SEQ, parity 0).
    const unsigned int tgf = (unsigned int)SEQ;
    float a0, a1, a2, a3;
    {
        unsigned long long v;
        do { v = mb_load(hbuf + tid);       } while ((unsigned)(v >> 32) != tgf);
        a0 = __uint_as_float((unsigned)v);
        do { v = mb_load(hbuf + tid + 256); } while ((unsigned)(v >> 32) != tgf);
        a1 = __uint_as_float((unsigned)v);
        do { v = mb_load(hbuf + tid + 512); } while ((unsigned)(v >> 32) != tgf);
        a2 = __uint_as_float((unsigned)v);
        do { v = mb_load(hbuf + tid + 768); } while ((unsigned)(v >> 32) != tgf);
        a3 = __uint_as_float((unsigned)v);
    }

    // Reproduce the previous kernel's reduction order exactly: 64-lane
    // butterfly per 64-element group g (group g = elements [64g,64g+64) =
    // our a_{g>>2} on wave g&3, lane e&63), then serial combine over the
    // 16 groups in order.
    __shared__ float rmax[16];
    __shared__ float rsum[16];

    float m0 = a0, m1 = a1, m2 = a2, m3 = a3;
    #pragma unroll
    for (int d = 1; d < 64; d <<= 1) {
        m0 = fmaxf(m0, __shfl_xor(m0, d));
        m1 = fmaxf(m1, __shfl_xor(m1, d));
        m2 = fmaxf(m2, __shfl_xor(m2, d));
        m3 = fmaxf(m3, __shfl_xor(m3, d));
    }
    if (lane == 0) {
        rmax[wv +  0] = m0;
        rmax[wv +  4] = m1;
        rmax[wv +  8] = m2;
        rmax[wv + 12] = m3;
    }
    __syncthreads();
    float gm = rmax[0];
    #pragma unroll
    for (int i = 1; i < 16; ++i) gm = fmaxf(gm, rmax[i]);

    float s0 = expf(a0 - gm), s1 = expf(a1 - gm);
    float s2 = expf(a2 - gm), s3 = expf(a3 - gm);
    #pragma unroll
    for (int d = 1; d < 64; d <<= 1) {
        s0 += __shfl_xor(s0, d);
        s1 += __shfl_xor(s1, d);
        s2 += __shfl_xor(s2, d);
        s3 += __shfl_xor(s3, d);
    }
    if (lane == 0) {
        rsum[wv +  0] = s0;
        rsum[wv +  4] = s1;
        rsum[wv +  8] = s2;
        rsum[wv + 12] = s3;
    }
    __syncthreads();
    float tot = rsum[0];
    #pragma unroll
    for (int i = 1; i < 16; ++i) tot += rsum[i];
    const float lse = gm + logf(tot);

    out[tid      ] = a0 - lse;
    out[tid + 256] = a1 - lse;
    out[tid + 512] = a2 - lse;
    out[tid + 768] = a3 - lse;
}

// ---------------------------------------------------------------------------
extern "C" void kernel_launch(void* const* d_in, const int* in_sizes, int n_in,
                              void* d_out, int out_size, void* d_ws, size_t ws_size,
                              hipStream_t stream)
{
    const int*   inputs = (const int*)d_in[0];
    const float* emb    = (const float*)d_in[1];
    const float* W_ih   = (const float*)d_in[2];
    const float* W_hh   = (const float*)d_in[3];
    const float* b_ih   = (const float*)d_in[4];
    const float* b_hh   = (const float*)d_in[5];
    const float* h0     = (const float*)d_in[6];
    const float* c0     = (const float*)d_in[7];
    float* out = (float*)d_out;

    // Workspace: [0, 64MB) xg ; [64MB, +16KB) hbuf (2 x 1024 u64).
    float* xg = (float*)d_ws;
    unsigned long long* hbuf =
        (unsigned long long*)((char*)d_ws + (size_t)SEQ * G4 * sizeof(float));

    dim3 g1(G4 / 64, SEQ / 64), b1(256);
    hipLaunchKernelGGL(xg_gemm_kernel, g1, b1, 0, stream,
                       inputs, emb, W_ih, b_ih, b_hh, xg);

    void* args[] = { (void*)&xg, (void*)&W_hh, (void*)&h0, (void*)&c0,
                     (void*)&hbuf, (void*)&out };
    hipLaunchCooperativeKernel((void*)lstm_kernel, dim3(256), dim3(256),
                               args, 0u, stream);
}

// Round 3
// 9908.360 us; speedup vs baseline: 1.5576x; 1.5576x over previous
//
#include <hip/hip_runtime.h>
#include <cmath>

// Problem constants (fixed by the reference).
#define SEQ   4096
#define INP   1024
#define HID   1024
#define G4    4096   // 4*HID

typedef float f32x2 __attribute__((ext_vector_type(2)));

// ---------------------------------------------------------------------------
__device__ __forceinline__ float fast_sigmoid(float x) {
    x = fminf(fmaxf(x, -30.f), 30.f);
    return __builtin_amdgcn_rcpf(1.0f + __expf(-x));
}
__device__ __forceinline__ float fast_tanh(float x) {
    x = fminf(fmaxf(x, -15.f), 15.f);
    float e = __expf(2.0f * x);
    return (e - 1.0f) * __builtin_amdgcn_rcpf(e + 1.0f);
}

__device__ __forceinline__ unsigned long long mb_load(const unsigned long long* p) {
    return __hip_atomic_load(p, __ATOMIC_RELAXED, __HIP_MEMORY_SCOPE_AGENT);
}

// DPP cross-lane move (VALU pipe, not LDS). CTRL: 0xB1=xor1 (quad_perm
// [1,0,3,2]), 0x4E=xor2 ([2,3,0,1]), 0x124=row_ror:4, 0x128=row_ror:8.
template <int CTRL>
__device__ __forceinline__ float dpp_mov(float x) {
    return __int_as_float(__builtin_amdgcn_update_dpp(
        0, __float_as_int(x), CTRL, 0xF, 0xF, true));
}

// ---------------------------------------------------------------------------
// Fused cooperative kernel: 256 WGs x 1024 threads, 1 WG/CU.
//
//   WGs 0..63   : persistent LSTM scan (R1 geometry, known-good: 8714us).
//   WGs 64..255 : xg GEMM producers, overlapped under the scan.
//
// R3 changes vs R1 (R2's 256-consumer spread REVERTED — it tripled comm):
//   1. xg GEMM fused as producer WGs on the 192 otherwise-idle CUs.
//      Producers compute 64x64 tiles (4 sub-blocks of the proven 256-thread
//      GEMM body per 1024-thread WG) in t-major order; after each tile:
//      __threadfence() (L2 writeback) + atomicAdd on the tile-row counter.
//      Consumers gate on cnt[t>>6]==64 once per 64 steps (acquire). Across
//      graph replays stale xg lines are benign (identical bytes every run);
//      counters are hipMemsetAsync-zeroed each launch.
//   2. Dot uses packed f32x2 accumulators (gates 0,1 | 2,3) -> v_pk_fma_f32,
//      halving dot-issue. Bit-exact: same per-gate k-order, fma both ways.
// ---------------------------------------------------------------------------
__global__ __launch_bounds__(1024, 4) void fused_kernel(
    const int*   __restrict__ inputs,
    const float* __restrict__ emb,
    const float* __restrict__ W_ih,
    const float* __restrict__ b_ih,
    const float* __restrict__ b_hh,
    const float* __restrict__ W_hh,
    const float* __restrict__ h0,
    const float* __restrict__ c0,
    float*       __restrict__ xg,            // workspace [SEQ][G4]
    unsigned long long* __restrict__ hbuf,   // 2 * 1024 entries
    int*         __restrict__ xgcnt,         // 64 tile-row counters
    float*       __restrict__ out)
{
    const int w   = blockIdx.x;
    const int tid = threadIdx.x;

    if (w >= 64) {
        // ================== xg GEMM producer (WGs 64..255) ==================
        // xg[t][r] = dot(emb[inputs[t]], W_ih[r]) + b_ih[r] + b_hh[r]
        // 4 sub-blocks x 256 threads, each a 64x64 tile (proven R0 body).
        __shared__ __align__(16) float As[4][16][68];
        __shared__ __align__(16) float Bs[4][16][68];
        __shared__ int toks[4][64];

        const int wgP = w - 64;          // 0..191
        const int sb  = tid >> 8;        // sub-block 0..3
        const int t2  = tid & 255;
        const int tx  = t2 & 15;
        const int ty  = t2 >> 4;
        const int si  = t2 >> 2;
        const int sk  = (t2 & 3) * 4;

        for (int it = 0; it < 6; ++it) {
            const int Q   = wgP + 192 * it;      // quad index
            const bool act = (Q < 1024);
            const int g   = Q * 4 + sb;          // tile 0..4095 (t-major)
            const int bt  = (g >> 6) * 64;       // t offset
            const int br  = (g & 63) * 64;       // gate-row offset

            if (act && t2 < 64) toks[sb][t2] = inputs[bt + t2];
            __syncthreads();

            float acc[4][4] = {};
            for (int kk = 0; kk < INP; kk += 16) {
                if (act) {
                    float4 av = *(const float4*)(emb  + (size_t)toks[sb][si] * INP + kk + sk);
                    float4 bv = *(const float4*)(W_ih + (size_t)(br + si) * INP + kk + sk);
                    As[sb][sk+0][si] = av.x; As[sb][sk+1][si] = av.y;
                    As[sb][sk+2][si] = av.z; As[sb][sk+3][si] = av.w;
                    Bs[sb][sk+0][si] = bv.x; Bs[sb][sk+1][si] = bv.y;
                    Bs[sb][sk+2][si] = bv.z; Bs[sb][sk+3][si] = bv.w;
                }
                __syncthreads();
                if (act) {
                    #pragma unroll
                    for (int k = 0; k < 16; ++k) {
                        float4 a = *(const float4*)&As[sb][k][ty * 4];
                        float4 b = *(const float4*)&Bs[sb][k][tx * 4];
                        float ar[4] = {a.x, a.y, a.z, a.w};
                        float brr[4] = {b.x, b.y, b.z, b.w};
                        #pragma unroll
                        for (int iy = 0; iy < 4; ++iy)
                            #pragma unroll
                            for (int ix = 0; ix < 4; ++ix)
                                acc[iy][ix] += ar[iy] * brr[ix];
                    }
                }
                __syncthreads();
            }

            if (act) {
                const int r0 = br + tx * 4;
                float4 bias;
                bias.x = b_ih[r0+0] + b_hh[r0+0];
                bias.y = b_ih[r0+1] + b_hh[r0+1];
                bias.z = b_ih[r0+2] + b_hh[r0+2];
                bias.w = b_ih[r0+3] + b_hh[r0+3];
                #pragma unroll
                for (int iy = 0; iy < 4; ++iy) {
                    float4 o;
                    o.x = acc[iy][0] + bias.x;
                    o.y = acc[iy][1] + bias.y;
                    o.z = acc[iy][2] + bias.z;
                    o.w = acc[iy][3] + bias.w;
                    *(float4*)(xg + (size_t)(bt + ty * 4 + iy) * G4 + r0) = o;
                }
            }
            __syncthreads();   // all sub-block stores issued before fence
            if (act && t2 == 0) {
                __threadfence();                      // L2 writeback (agent)
                atomicAdd(xgcnt + (g >> 6), 1);       // publish tile-row progress
            }
        }
        return;
    }

    // ====================== LSTM consumer (WGs 0..63) =======================
    const int lane = tid & 63;
    const int wv   = tid >> 6;     // wave 0..15 -> h element j = w*16+wv
    const int qq   = lane >> 4;    // 16-lane group 0..3 (h-slice quarter)
    const int kc   = lane & 15;    // 64-float h chunk index
    const int j    = w * 16 + wv;

    // Persistent W fragment, gate-paired for v_pk_fma_f32:
    // wp01[e] = {W_hh[0*H+j][o+e], W_hh[1*H+j][o+e]}, wp23 likewise (2,3),
    // o = kc*64 + qq*16. Same values, same per-gate k-order as before.
    f32x2 wp01[16], wp23[16];
    {
        const int o = kc * 64 + qq * 16;
        const float* r0p = W_hh + (size_t)(0 * HID + j) * HID + o;
        const float* r1p = W_hh + (size_t)(1 * HID + j) * HID + o;
        const float* r2p = W_hh + (size_t)(2 * HID + j) * HID + o;
        const float* r3p = W_hh + (size_t)(3 * HID + j) * HID + o;
        #pragma unroll
        for (int m = 0; m < 4; ++m) {
            float4 a0 = *(const float4*)(r0p + 4 * m);
            float4 a1 = *(const float4*)(r1p + 4 * m);
            float4 a2 = *(const float4*)(r2p + 4 * m);
            float4 a3 = *(const float4*)(r3p + 4 * m);
            wp01[4*m+0] = (f32x2){a0.x, a1.x}; wp23[4*m+0] = (f32x2){a2.x, a3.x};
            wp01[4*m+1] = (f32x2){a0.y, a1.y}; wp23[4*m+1] = (f32x2){a2.y, a3.y};
            wp01[4*m+2] = (f32x2){a0.z, a1.z}; wp23[4*m+2] = (f32x2){a2.z, a3.z};
            wp01[4*m+3] = (f32x2){a0.w, a1.w}; wp23[4*m+3] = (f32x2){a2.w, a3.w};
        }
    }

    float c = c0[j];

    // Seed h0 with tag 0 (parity 0): wave 0 lanes 0..15, full-line store.
    if (wv == 0 && lane < 16) {
        unsigned long long pk =
            (unsigned long long)__float_as_uint(h0[w * 16 + lane]);
        __hip_atomic_store(hbuf + w * 16 + lane, pk,
                           __ATOMIC_RELAXED, __HIP_MEMORY_SCOPE_AGENT);
    }

    __shared__ __align__(16) float hs[16 * 68];  // h chunks, stride 68
    __shared__ float xgs[64];                    // xg: gate q, elem wv -> q*16+wv
    __shared__ float hout[16];                   // this WG's 16 new h values

    const int lofs = (tid >> 6) * 68 + (tid & 63);   // write slot for polled h
    const bool hasx = (tid < 64);
    const size_t xgofs = (size_t)(tid >> 4) * HID + w * 16 + (tid & 15);
    const float* hp = hs + kc * 68 + qq * 16;        // private 16-elem slice

    for (int t = 0; t < SEQ; ++t) {
        const int par = t & 1;
        const unsigned long long* slot = hbuf + (size_t)par * 1024 + tid;

        // Gate on xg tile-row availability once per 64 steps (producers run
        // ~9x faster than consumption; this waits only at t=0, ~10us).
        if ((t & 63) == 0) {
            while (__hip_atomic_load(xgcnt + (t >> 6), __ATOMIC_ACQUIRE,
                                     __HIP_MEMORY_SCOPE_AGENT) != 64) {}
        }

        // xg load issued before the poll; latency hides under the wait.
        float xv = 0.f;
        if (hasx) xv = xg[(size_t)t * G4 + xgofs];

        // 4-deep pipelined poll of this thread's single entry.
        const unsigned int tg = (unsigned int)t;
        unsigned long long v;
        {
            unsigned long long p0 = mb_load(slot);
            unsigned long long p1 = mb_load(slot);
            unsigned long long p2 = mb_load(slot);
            unsigned long long p3 = mb_load(slot);
            for (;;) {
                if ((unsigned int)(p0 >> 32) == tg) { v = p0; break; }
                p0 = mb_load(slot);
                if ((unsigned int)(p1 >> 32) == tg) { v = p1; break; }
                p1 = mb_load(slot);
                if ((unsigned int)(p2 >> 32) == tg) { v = p2; break; }
                p2 = mb_load(slot);
                if ((unsigned int)(p3 >> 32) == tg) { v = p3; break; }
                p3 = mb_load(slot);
            }
        }

        hs[lofs] = __uint_as_float((unsigned int)v);
        if (hasx) xgs[tid] = xv;
        __syncthreads();  // B1

        // Packed partial dots: gates (0,1) and (2,3) share a f32x2 lane.
        f32x2 p01 = {0.f, 0.f}, p23 = {0.f, 0.f};
        #pragma unroll
        for (int m = 0; m < 4; ++m) {
            float4 hv = *(const float4*)(hp + 4 * m);
            f32x2 h0v = {hv.x, hv.x}, h1v = {hv.y, hv.y};
            f32x2 h2v = {hv.z, hv.z}, h3v = {hv.w, hv.w};
            p01 += wp01[4*m+0] * h0v;  p23 += wp23[4*m+0] * h0v;
            p01 += wp01[4*m+1] * h1v;  p23 += wp23[4*m+1] * h1v;
            p01 += wp01[4*m+2] * h2v;  p23 += wp23[4*m+2] * h2v;
            p01 += wp01[4*m+3] * h3v;  p23 += wp23[4*m+3] * h3v;
        }
        float p[4] = {p01.x, p01.y, p23.x, p23.y};

        // 64-lane butterfly reduction of the 4 accumulators (identical).
        #pragma unroll
        for (int q = 0; q < 4; ++q) {
            p[q] += dpp_mov<0xB1>(p[q]);
            p[q] += dpp_mov<0x4E>(p[q]);
            p[q] += dpp_mov<0x124>(p[q]);
            p[q] += dpp_mov<0x128>(p[q]);
            p[q] += __shfl_xor(p[q], 16);
            p[q] += __shfl_xor(p[q], 32);
        }

        float gi = p[0] + xgs[ 0 + wv];
        float gf = p[1] + xgs[16 + wv];
        float gg = p[2] + xgs[32 + wv];
        float go = p[3] + xgs[48 + wv];

        float ig = fast_sigmoid(gi);
        float fg = fast_sigmoid(gf);
        float gc = fast_tanh(gg);
        float og = fast_sigmoid(go);
        c = fg * c + ig * gc;
        float h = og * fast_tanh(c);

        if (lane == 0) hout[wv] = h;
        __syncthreads();  // B2

        // Wave 0, lanes 0..15: publish 16 tagged entries -> two full 64B lines.
        if (wv == 0 && lane < 16) {
            unsigned long long pk =
                ((unsigned long long)(unsigned int)(t + 1) << 32) |
                (unsigned long long)__float_as_uint(hout[lane]);
            __hip_atomic_store(
                hbuf + (size_t)((t + 1) & 1) * 1024 + w * 16 + lane, pk,
                __ATOMIC_RELAXED, __HIP_MEMORY_SCOPE_AGENT);
        }
        // hs/xgs single buffer safe: next step's writes ordered after B2.
    }

    // ------------------- final log_softmax (WG 0 only) -------------------
    if (w != 0) return;

    float a;
    {
        const unsigned int tg = (unsigned int)SEQ;  // SEQ even -> parity 0
        const unsigned long long* slot = hbuf + tid;
        unsigned long long v;
        do {
            v = mb_load(slot);
        } while ((unsigned int)(v >> 32) != tg);
        a = __uint_as_float((unsigned int)v);
    }

    __shared__ float rmax[16];
    __shared__ float rsum[16];

    float lm = a;
    #pragma unroll
    for (int d = 1; d < 64; d <<= 1) lm = fmaxf(lm, __shfl_xor(lm, d));
    if (lane == 0) rmax[wv] = lm;
    __syncthreads();
    float gm = rmax[0];
    #pragma unroll
    for (int i = 1; i < 16; ++i) gm = fmaxf(gm, rmax[i]);

    float ls = expf(a - gm);
    #pragma unroll
    for (int d = 1; d < 64; d <<= 1) ls += __shfl_xor(ls, d);
    if (lane == 0) rsum[wv] = ls;
    __syncthreads();
    float tot = rsum[0];
    #pragma unroll
    for (int i = 1; i < 16; ++i) tot += rsum[i];
    const float lse = gm + logf(tot);

    out[tid] = a - lse;
}

// ---------------------------------------------------------------------------
extern "C" void kernel_launch(void* const* d_in, const int* in_sizes, int n_in,
                              void* d_out, int out_size, void* d_ws, size_t ws_size,
                              hipStream_t stream)
{
    const int*   inputs = (const int*)d_in[0];
    const float* emb    = (const float*)d_in[1];
    const float* W_ih   = (const float*)d_in[2];
    const float* W_hh   = (const float*)d_in[3];
    const float* b_ih   = (const float*)d_in[4];
    const float* b_hh   = (const float*)d_in[5];
    const float* h0     = (const float*)d_in[6];
    const float* c0     = (const float*)d_in[7];
    float* out = (float*)d_out;

    // Workspace: [0, 64MB) xg ; [+16KB) hbuf (2x1024 u64) ; [+256B) xgcnt.
    const size_t XG_BYTES   = (size_t)SEQ * G4 * sizeof(float);
    const size_t HBUF_BYTES = 2 * 1024 * sizeof(unsigned long long);
    float* xg = (float*)d_ws;
    unsigned long long* hbuf =
        (unsigned long long*)((char*)d_ws + XG_BYTES);
    int* xgcnt = (int*)((char*)d_ws + XG_BYTES + HBUF_BYTES);

    hipMemsetAsync(xgcnt, 0, 64 * sizeof(int), stream);

    void* args[] = { (void*)&inputs, (void*)&emb, (void*)&W_ih,
                     (void*)&b_ih, (void*)&b_hh, (void*)&W_hh,
                     (void*)&h0, (void*)&c0,
                     (void*)&xg, (void*)&hbuf, (void*)&xgcnt, (void*)&out };
    hipLaunchCooperativeKernel((void*)fused_kernel, dim3(256), dim3(1024),
                               args, 0u, stream);
}